// Round 3
// baseline (637.775 us; speedup 1.0000x reference)
//
#include <hip/hip_runtime.h>
#include <hip/hip_bf16.h>

// ---------------- problem constants ----------------
#define S_LEN   2048
#define HID_SZ  4096
#define NH      32
#define NKV     8
#define HD      128
#define EPS_F   1e-6f
#define SM_SCALE 0.08838834764831845f   // 1/sqrt(128)

typedef __attribute__((ext_vector_type(8))) short bf16x8;   // 8 bf16 (4 VGPRs) — MFMA A/B frag
typedef __attribute__((ext_vector_type(4))) float f32x4;    // MFMA C/D frag

#define AS1(p) ((__attribute__((address_space(1))) void*)(p))
#define AS3(p) ((__attribute__((address_space(3))) void*)(p))

__device__ __forceinline__ short f2b(float f) {
  // fp32 -> bf16 RNE
  unsigned u = __builtin_bit_cast(unsigned, f);
  unsigned r = (u + 0x7fffu + ((u >> 16) & 1u)) >> 16;
  return (short)(unsigned short)r;
}

// ---------------- fp32 -> bf16 bulk convert (vectorized, G13) ----------------
__global__ __launch_bounds__(256) void cvt_f32_bf16(const float* __restrict__ in,
                                                    short* __restrict__ out, int n4) {
  int i = blockIdx.x * 256 + threadIdx.x;
  if (i >= n4) return;
  float4 f = reinterpret_cast<const float4*>(in)[i];
  short4 o;
  o.x = f2b(f.x); o.y = f2b(f.y); o.z = f2b(f.z); o.w = f2b(f.w);
  reinterpret_cast<short4*>(out)[i] = o;
}

// ---------------- RoPE cos/sin tables [S][64] ----------------
__global__ void rope_tables_k(float* __restrict__ cosT, float* __restrict__ sinT) {
  int s = blockIdx.x;
  int j = threadIdx.x;                       // 0..63
  // theta_j = BASE^(-2j/128) = 2^(-(2j/128)*log2(1e6))
  float theta = exp2f(-(float)(2 * j) * (19.931568569324174f / 128.0f));
  float ang = (float)s * theta;
  float sv, cv;
  sincosf(ang, &sv, &cv);
  cosT[s * 64 + j] = cv;
  sinT[s * 64 + j] = sv;
}

// ---------------- fused RMSNorm (per head) + RoPE, fp32 in -> bf16 [h][s][d] out ----------------
__global__ __launch_bounds__(256)
void rmsrope_k(const float* __restrict__ src, int srcStride, int srcCol,
               const float* __restrict__ w,
               const float* __restrict__ cosT, const float* __restrict__ sinT,
               short* __restrict__ dst, int heads) {
  int gw   = blockIdx.x * 4 + (threadIdx.x >> 6);   // one wave per (s, h)
  int lane = threadIdx.x & 63;
  int s = gw / heads;
  int h = gw - s * heads;
  const float* p = src + (size_t)s * srcStride + srcCol + h * HD;
  float x0 = p[lane], x1 = p[lane + 64];
  float ss = x0 * x0 + x1 * x1;
#pragma unroll
  for (int off = 1; off < 64; off <<= 1) ss += __shfl_xor(ss, off);
  float r = rsqrtf(ss * (1.0f / 128.0f) + EPS_F);
  float y0 = x0 * r * w[lane];
  float y1 = x1 * r * w[lane + 64];
  // rotate_half: out[d] = x[d]*cos - x[d+64]*sin ; out[d+64] = x[d+64]*cos + x[d]*sin
  float c = cosT[s * 64 + lane], sn = sinT[s * 64 + lane];
  float o0 = y0 * c - y1 * sn;
  float o1 = y1 * c + y0 * sn;
  short* d = dst + ((size_t)h * S_LEN + s) * HD;
  d[lane]      = f2b(o0);
  d[lane + 64] = f2b(o1);
}

// ---------------- V transpose: qkv fp32 [s][6144] (v at col 5120) -> vt bf16 [kv][d][s] ----------------
__global__ __launch_bounds__(256)
void vtrans_k(const float* __restrict__ qkv, short* __restrict__ vt) {
  __shared__ float t[64][65];           // +1 pad: conflict-free column reads
  int s0 = blockIdx.x * 64;
  int d0 = blockIdx.y * 64;
  int kv = blockIdx.z;
  int j  = threadIdx.x & 63;
  int i0 = threadIdx.x >> 6;
#pragma unroll
  for (int r = 0; r < 16; ++r) {
    int i = i0 * 16 + r;
    t[i][j] = qkv[(size_t)(s0 + i) * 6144 + 5120 + kv * HD + d0 + j];
  }
  __syncthreads();
#pragma unroll
  for (int r = 0; r < 16; ++r) {
    int i = i0 * 16 + r;                // i = d index, j = s index
    vt[((size_t)kv * HD + d0 + i) * S_LEN + s0 + j] = f2b(t[j][i]);
  }
}

// ---------------- bf16 GEMM: C[M,N] (fp32) = A[M,K] @ B[N,K]^T ----------------
// m97 structure: 128x128 tile, BK=32, 4 waves (2x2), 4x4 16x16 frags/wave,
// global_load_lds width-16 staging into linear LDS.
__global__ __launch_bounds__(256)
void gemm_bt_k(const short* __restrict__ A, const short* __restrict__ B,
               float* __restrict__ C, int M, int N, int K) {
  __shared__ short As[128 * 32];
  __shared__ short Bs[128 * 32];
  int tid  = threadIdx.x;
  int lane = tid & 63;
  int wave = tid >> 6;
  int wr = wave >> 1, wc = wave & 1;
  int m0 = blockIdx.y * 128, n0 = blockIdx.x * 128;
  f32x4 acc[4][4] = {};
  int row16 = lane & 15;
  int kg    = (lane >> 4) << 3;        // k offset 0/8/16/24 within BK
  // staging: 16B chunk c -> LDS byte c*16 (linear), global row c>>2, col-chunk c&3
  int c0 = tid, c1 = tid + 256;
  const size_t rA0 = (size_t)(m0 + (c0 >> 2)) * K + ((c0 & 3) << 3);
  const size_t rA1 = (size_t)(m0 + (c1 >> 2)) * K + ((c1 & 3) << 3);
  const size_t rB0 = (size_t)(n0 + (c0 >> 2)) * K + ((c0 & 3) << 3);
  const size_t rB1 = (size_t)(n0 + (c1 >> 2)) * K + ((c1 & 3) << 3);
  for (int kt = 0; kt < K; kt += 32) {
    __builtin_amdgcn_global_load_lds(AS1(A + rA0 + kt), AS3(&As[c0 * 8]), 16, 0, 0);
    __builtin_amdgcn_global_load_lds(AS1(A + rA1 + kt), AS3(&As[c1 * 8]), 16, 0, 0);
    __builtin_amdgcn_global_load_lds(AS1(B + rB0 + kt), AS3(&Bs[c0 * 8]), 16, 0, 0);
    __builtin_amdgcn_global_load_lds(AS1(B + rB1 + kt), AS3(&Bs[c1 * 8]), 16, 0, 0);
    __syncthreads();                   // compiler drains vmcnt before barrier
    bf16x8 af[4], bf[4];
#pragma unroll
    for (int i = 0; i < 4; ++i)
      af[i] = *reinterpret_cast<const bf16x8*>(&As[(wr * 64 + i * 16 + row16) * 32 + kg]);
#pragma unroll
    for (int j = 0; j < 4; ++j)
      bf[j] = *reinterpret_cast<const bf16x8*>(&Bs[(wc * 64 + j * 16 + row16) * 32 + kg]);
#pragma unroll
    for (int i = 0; i < 4; ++i)
#pragma unroll
      for (int j = 0; j < 4; ++j)
        acc[i][j] = __builtin_amdgcn_mfma_f32_16x16x32_bf16(af[i], bf[j], acc[i][j], 0, 0, 0);
    __syncthreads();
  }
  // epilogue: C/D layout col=lane&15, row=(lane>>4)*4+reg (m89-verified)
  int rsub = (lane >> 4) << 2;
#pragma unroll
  for (int i = 0; i < 4; ++i)
#pragma unroll
    for (int j = 0; j < 4; ++j) {
      size_t base = (size_t)(m0 + wr * 64 + i * 16 + rsub) * N + (n0 + wc * 64 + j * 16 + row16);
#pragma unroll
      for (int reg = 0; reg < 4; ++reg)
        C[base + (size_t)reg * N] = acc[i][j][reg];
    }
}

// ---------------- flash attention (causal, GQA) ----------------
// grid (32 qblocks, 32 heads); 4 waves x 16 q-rows; KV tile = 64.
// Qr [H][S][D] bf16, Kr [KV][S][D] bf16, Vt [KV][D][S] bf16, Ob [S][H*D] bf16.
// K/V staged via global_load_lds(16B) into LINEAR LDS with XOR-pre-swizzled
// SOURCE (rule #21: both-sides-or-neither); reads XOR byte bits 4..6 with
// (row&7)<<4 -> conflict-free ds_read_b128 on both K (256B rows) and V (128B rows).
__global__ __launch_bounds__(256)
void attn_k(const short* __restrict__ Qr, const short* __restrict__ Kr,
            const short* __restrict__ Vt, short* __restrict__ Ob) {
  constexpr int PP = 72;              // P_lds row stride (shorts): 64+8 pad
  __shared__ short Kl[64 * 128];      // 16 KB, linear (swizzled content)
  __shared__ short Vl[128 * 64];      // 16 KB, linear (swizzled content)
  __shared__ short Pl[4][16 * PP];    //  9 KB (per-wave slice)
  int qb = (int)gridDim.x - 1 - (int)blockIdx.x;   // heavy blocks first (causal tail)
  int h  = blockIdx.y;
  int kvh = h >> 2;                                // G = H/KV = 4
  int tid = threadIdx.x, wave = tid >> 6, lane = tid & 63;
  int row16 = lane & 15, kg = (lane >> 4) << 3, rsub = (lane >> 4) << 2;
  int colb  = (lane >> 4) << 4;       // byte col offset of this lane's k-group
  int swz   = (row16 & 7) << 4;       // read-side XOR (row&7 == row16&7: tiles 16-row aligned)
  int qrow0 = qb * 64 + wave * 16;

  bf16x8 qf[4];
  {
    const short* qp = Qr + ((size_t)h * S_LEN + qrow0 + row16) * HD + kg;
#pragma unroll
    for (int ks = 0; ks < 4; ++ks)
      qf[ks] = *reinterpret_cast<const bf16x8*>(qp + ks * 32);
  }
  f32x4 o[8] = {};                   // O[16][128] accumulator (C layout)
  float mrow[4], lrow[4];
#pragma unroll
  for (int r = 0; r < 4; ++r) { mrow[r] = -3.0e38f; lrow[r] = 0.0f; }

  const short* Kb = Kr + (size_t)kvh * S_LEN * HD;
  const short* Vb = Vt + (size_t)kvh * HD * S_LEN;

  for (int kt = 0; kt <= qb; ++kt) {
    // ---- stage K [64][128] (1024 x 16B chunks) ----
    const short* Kt = Kb + (size_t)kt * 64 * HD;
#pragma unroll
    for (int r = 0; r < 4; ++r) {
      int c = tid + r * 256;                      // LDS chunk id
      int krow = c >> 4, ch = c & 15;
      int sch = (ch & 8) | ((ch ^ krow) & 7);     // inverse-swizzled source chunk
      __builtin_amdgcn_global_load_lds(AS1(Kt + krow * HD + sch * 8),
                                       AS3(&Kl[c * 8]), 16, 0, 0);
    }
    // ---- stage V^T [128][64] (1024 x 16B chunks) ----
#pragma unroll
    for (int r = 0; r < 4; ++r) {
      int c = tid + r * 256;
      int dr = c >> 3, ch = c & 7;
      int sch = (ch ^ dr) & 7;
      __builtin_amdgcn_global_load_lds(AS1(Vb + (size_t)dr * S_LEN + kt * 64 + sch * 8),
                                       AS3(&Vl[c * 8]), 16, 0, 0);
    }
    __syncthreads();

    // S = Q K^T  (16 rows x 64 keys per wave)
    f32x4 s4[4];
#pragma unroll
    for (int nc = 0; nc < 4; ++nc) {
      int R = nc * 16 + row16;
      const char* rowp = (const char*)Kl + R * 256;
      f32x4 a = {};
#pragma unroll
      for (int ks = 0; ks < 4; ++ks) {
        bf16x8 kf = *reinterpret_cast<const bf16x8*>(rowp + ((ks * 64 + colb) ^ swz));
        a = __builtin_amdgcn_mfma_f32_16x16x32_bf16(qf[ks], kf, a, 0, 0, 0);
      }
      s4[nc] = a;
    }

    // scale + causal mask + tile row-max
    bool diag = (kt == qb);
    float mt[4] = {-3.0e38f, -3.0e38f, -3.0e38f, -3.0e38f};
#pragma unroll
    for (int nc = 0; nc < 4; ++nc)
#pragma unroll
      for (int reg = 0; reg < 4; ++reg) {
        float v = s4[nc][reg] * SM_SCALE;
        if (diag && (kt * 64 + nc * 16 + row16) > (qrow0 + rsub + reg)) v = -3.0e38f;
        s4[nc][reg] = v;
        mt[reg] = fmaxf(mt[reg], v);
      }
#pragma unroll
    for (int reg = 0; reg < 4; ++reg)
#pragma unroll
      for (int off = 1; off < 16; off <<= 1)
        mt[reg] = fmaxf(mt[reg], __shfl_xor(mt[reg], off));

    // online softmax update
    float sc[4], st[4];
#pragma unroll
    for (int reg = 0; reg < 4; ++reg) {
      float mnew = fmaxf(mrow[reg], mt[reg]);
      sc[reg] = __expf(mrow[reg] - mnew);
      mrow[reg] = mnew;
      st[reg] = 0.0f;
    }
#pragma unroll
    for (int nc = 0; nc < 4; ++nc)
#pragma unroll
      for (int reg = 0; reg < 4; ++reg) {
        float p = __expf(s4[nc][reg] - mrow[reg]);
        s4[nc][reg] = p;
        st[reg] += p;
      }
#pragma unroll
    for (int reg = 0; reg < 4; ++reg) {
#pragma unroll
      for (int off = 1; off < 16; off <<= 1)
        st[reg] += __shfl_xor(st[reg], off);
      lrow[reg] = lrow[reg] * sc[reg] + st[reg];
    }
#pragma unroll
    for (int i = 0; i < 8; ++i) {
      f32x4 t = o[i];
      t[0] *= sc[0]; t[1] *= sc[1]; t[2] *= sc[2]; t[3] *= sc[3];
      o[i] = t;
    }

    // P -> LDS (C layout -> [row][key]) then back as A-frag (same-wave RAW; DS pipe in-order)
#pragma unroll
    for (int nc = 0; nc < 4; ++nc)
#pragma unroll
      for (int reg = 0; reg < 4; ++reg)
        Pl[wave][(rsub + reg) * PP + nc * 16 + row16] = f2b(s4[nc][reg]);

    // O += P V
#pragma unroll
    for (int ks = 0; ks < 2; ++ks) {
      bf16x8 pf = *reinterpret_cast<const bf16x8*>(&Pl[wave][row16 * PP + ks * 32 + kg]);
#pragma unroll
      for (int nc = 0; nc < 8; ++nc) {
        int R = nc * 16 + row16;
        const char* rowp = (const char*)Vl + R * 128;
        bf16x8 vf = *reinterpret_cast<const bf16x8*>(rowp + ((ks * 64 + colb) ^ swz));
        o[nc] = __builtin_amdgcn_mfma_f32_16x16x32_bf16(pf, vf, o[nc], 0, 0, 0);
      }
    }
    __syncthreads();
  }

  // epilogue: O /= l, write [S][H*D] bf16
#pragma unroll
  for (int nc = 0; nc < 8; ++nc)
#pragma unroll
    for (int reg = 0; reg < 4; ++reg) {
      float val = o[nc][reg] * (1.0f / lrow[reg]);
      int srow = qrow0 + rsub + reg;
      Ob[(size_t)srow * HID_SZ + h * HD + nc * 16 + row16] = f2b(val);
    }
}

// ---------------- launch ----------------
extern "C" void kernel_launch(void* const* d_in, const int* in_sizes, int n_in,
                              void* d_out, int out_size, void* d_ws, size_t ws_size,
                              hipStream_t stream) {
  const float* x   = (const float*)d_in[0];
  const float* wq  = (const float*)d_in[1];
  const float* wk  = (const float*)d_in[2];
  const float* wv  = (const float*)d_in[3];
  const float* wo  = (const float*)d_in[4];
  const float* qnw = (const float*)d_in[5];
  const float* knw = (const float*)d_in[6];
  float* out = (float*)d_out;

  // workspace layout (aliased; 137 MB total):
  //   [0,16M)    xb  bf16 [2048][4096]   -> later attnb bf16 [2048][4096]
  //   [16M,64M)  wqkvb bf16 [6144][4096] -> later wob bf16 [4096][4096] (32M)
  //   [64M,112M) qkvf fp32 [2048][6144]
  //   [112M,128M) qr bf16 [32][2048][128]
  //   [128M,132M) kr bf16 [8][2048][128]
  //   [132M,136M) vt bf16 [8][128][2048]
  //   [136M,137M) cosT/sinT fp32 [2048][64]
  char* ws = (char*)d_ws;
  short* xb    = (short*)(ws);
  short* attnb = (short*)(ws);                        // aliases xb (dead after QKV GEMM)
  short* wqkvb = (short*)(ws + (16ull  << 20));
  short* wob   = (short*)(ws + (16ull  << 20));       // aliases wqkvb (dead after QKV GEMM)
  float* qkvf  = (float*)(ws + (64ull  << 20));
  short* qr    = (short*)(ws + (112ull << 20));
  short* kr    = (short*)(ws + (128ull << 20));
  short* vt    = (short*)(ws + (132ull << 20));
  float* cosT  = (float*)(ws + (136ull << 20));
  float* sinT  = (float*)(ws + (136ull << 20) + (512ull << 10));

  // 1) convert x + packed [wq;wk;wv] to bf16
  cvt_f32_bf16<<<8192,  256, 0, stream>>>(x,  xb,    2097152);
  cvt_f32_bf16<<<16384, 256, 0, stream>>>(wq, wqkvb,                       4194304);
  cvt_f32_bf16<<<4096,  256, 0, stream>>>(wk, wqkvb + (size_t)4096 * 4096, 1048576);
  cvt_f32_bf16<<<4096,  256, 0, stream>>>(wv, wqkvb + (size_t)5120 * 4096, 1048576);

  // 2) RoPE tables
  rope_tables_k<<<2048, 64, 0, stream>>>(cosT, sinT);

  // 3) fused QKV projection: [2048,6144] = xb @ wqkvb^T
  gemm_bt_k<<<dim3(48, 16), 256, 0, stream>>>(xb, wqkvb, qkvf, 2048, 6144, 4096);

  // 4) wo -> bf16 (after QKV GEMM: overwrites wqkvb region)
  cvt_f32_bf16<<<16384, 256, 0, stream>>>(wo, wob, 4194304);

  // 5) RMSNorm + RoPE -> Q [H][S][D], K [KV][S][D]; V -> [KV][D][S]
  rmsrope_k<<<16384, 256, 0, stream>>>(qkvf, 6144, 0,    qnw, cosT, sinT, qr, NH);
  rmsrope_k<<<4096,  256, 0, stream>>>(qkvf, 6144, 4096, knw, cosT, sinT, kr, NKV);
  vtrans_k<<<dim3(32, 2, 8), 256, 0, stream>>>(qkvf, vt);

  // 6) causal GQA flash attention -> attnb [S][H*D] bf16 (overwrites xb region)
  attn_k<<<dim3(32, 32), 256, 0, stream>>>(qr, kr, vt, attnb);

  // 7) output projection -> d_out fp32
  gemm_bt_k<<<dim3(32, 16), 256, 0, stream>>>(attnb, wob, out, 2048, 4096, 4096);

  (void)in_sizes; (void)n_in; (void)out_size; (void)ws_size;
}

// Round 4
// 555.303 us; speedup vs baseline: 1.1485x; 1.1485x over previous
//
#include <hip/hip_runtime.h>
#include <hip/hip_bf16.h>

// ---------------- problem constants ----------------
#define S_LEN   2048
#define HID_SZ  4096
#define NH      32
#define NKV     8
#define HD      128
#define EPS_F   1e-6f
// SM_SCALE * log2(e): folded into Q at rmsrope time; attn uses exp2 domain.
#define QSCALE  0.1275174475f

typedef __attribute__((ext_vector_type(8))) short bf16x8;   // 8 bf16 (4 VGPRs) — MFMA A/B frag
typedef __attribute__((ext_vector_type(4))) float f32x4;    // MFMA C/D frag

#define AS1(p) ((__attribute__((address_space(1))) void*)(p))
#define AS3(p) ((__attribute__((address_space(3))) void*)(p))

__device__ __forceinline__ short f2b(float f) {
  // fp32 -> bf16 RNE
  unsigned u = __builtin_bit_cast(unsigned, f);
  unsigned r = (u + 0x7fffu + ((u >> 16) & 1u)) >> 16;
  return (short)(unsigned short)r;
}
__device__ __forceinline__ float b2f(short s) {
  return __builtin_bit_cast(float, (unsigned)((unsigned short)s) << 16);
}

// ---------------- fp32 -> bf16 bulk convert (vectorized, G13) ----------------
__global__ __launch_bounds__(256) void cvt_f32_bf16(const float* __restrict__ in,
                                                    short* __restrict__ out, int n4) {
  int i = blockIdx.x * 256 + threadIdx.x;
  if (i >= n4) return;
  float4 f = reinterpret_cast<const float4*>(in)[i];
  short4 o;
  o.x = f2b(f.x); o.y = f2b(f.y); o.z = f2b(f.z); o.w = f2b(f.w);
  reinterpret_cast<short4*>(out)[i] = o;
}

// ---------------- RoPE cos/sin tables [S][64] ----------------
__global__ void rope_tables_k(float* __restrict__ cosT, float* __restrict__ sinT) {
  int s = blockIdx.x;
  int j = threadIdx.x;                       // 0..63
  float theta = exp2f(-(float)(2 * j) * (19.931568569324174f / 128.0f));
  float ang = (float)s * theta;
  float sv, cv;
  sincosf(ang, &sv, &cv);
  cosT[s * 64 + j] = cv;
  sinT[s * 64 + j] = sv;
}

// ------- fused RMSNorm (per head) + RoPE, bf16 qkv in -> bf16 [h][s][d] out -------
__global__ __launch_bounds__(256)
void rmsrope_k(const short* __restrict__ src, int srcCol,
               const float* __restrict__ w,
               const float* __restrict__ cosT, const float* __restrict__ sinT,
               short* __restrict__ dst, int heads, float outScale) {
  int gw   = blockIdx.x * 4 + (threadIdx.x >> 6);   // one wave per (s, h)
  int lane = threadIdx.x & 63;
  int s = gw / heads;
  int h = gw - s * heads;
  const short* p = src + (size_t)s * 6144 + srcCol + h * HD;
  float x0 = b2f(p[lane]), x1 = b2f(p[lane + 64]);
  float ss = x0 * x0 + x1 * x1;
#pragma unroll
  for (int off = 1; off < 64; off <<= 1) ss += __shfl_xor(ss, off);
  float r = rsqrtf(ss * (1.0f / 128.0f) + EPS_F);
  float y0 = x0 * r * w[lane];
  float y1 = x1 * r * w[lane + 64];
  // rotate_half: out[d] = x[d]*cos - x[d+64]*sin ; out[d+64] = x[d+64]*cos + x[d]*sin
  float c = cosT[s * 64 + lane], sn = sinT[s * 64 + lane];
  float o0 = (y0 * c - y1 * sn) * outScale;
  float o1 = (y1 * c + y0 * sn) * outScale;
  short* d = dst + ((size_t)h * S_LEN + s) * HD;
  d[lane]      = f2b(o0);
  d[lane + 64] = f2b(o1);
}

// ------- V transpose: qkv bf16 [s][6144] (v at col 5120) -> vt bf16 [kv][d][s] -------
__global__ __launch_bounds__(256)
void vtrans_k(const short* __restrict__ qkvb, short* __restrict__ vt) {
  __shared__ short t[64][65];           // +1 pad
  int s0 = blockIdx.x * 64;
  int d0 = blockIdx.y * 64;
  int kv = blockIdx.z;
  int j  = threadIdx.x & 63;
  int i0 = threadIdx.x >> 6;
#pragma unroll
  for (int r = 0; r < 16; ++r) {
    int i = i0 * 16 + r;
    t[i][j] = qkvb[(size_t)(s0 + i) * 6144 + 5120 + kv * HD + d0 + j];
  }
  __syncthreads();
#pragma unroll
  for (int r = 0; r < 16; ++r) {
    int i = i0 * 16 + r;                // i = d index, j = s index
    vt[((size_t)kv * HD + d0 + i) * S_LEN + s0 + j] = t[j][i];
  }
}

// ---------------- bf16 GEMM: C[M,N] = A[M,K] @ B[N,K]^T ----------------
// m97 structure: 128x128 tile, BK=32, 4 waves (2x2), 4x4 16x16 frags/wave,
// global_load_lds width-16 staging into linear LDS. Output fp32 or bf16.
template<bool BF16OUT>
__global__ __launch_bounds__(256)
void gemm_bt_k(const short* __restrict__ A, const short* __restrict__ B,
               void* __restrict__ Cv, int M, int N, int K) {
  __shared__ short As[128 * 32];
  __shared__ short Bs[128 * 32];
  int tid  = threadIdx.x;
  int lane = tid & 63;
  int wave = tid >> 6;
  int wr = wave >> 1, wc = wave & 1;
  int m0 = blockIdx.y * 128, n0 = blockIdx.x * 128;
  f32x4 acc[4][4] = {};
  int row16 = lane & 15;
  int kg    = (lane >> 4) << 3;        // k offset 0/8/16/24 within BK
  int c0 = tid, c1 = tid + 256;
  const size_t rA0 = (size_t)(m0 + (c0 >> 2)) * K + ((c0 & 3) << 3);
  const size_t rA1 = (size_t)(m0 + (c1 >> 2)) * K + ((c1 & 3) << 3);
  const size_t rB0 = (size_t)(n0 + (c0 >> 2)) * K + ((c0 & 3) << 3);
  const size_t rB1 = (size_t)(n0 + (c1 >> 2)) * K + ((c1 & 3) << 3);
  for (int kt = 0; kt < K; kt += 32) {
    __builtin_amdgcn_global_load_lds(AS1(A + rA0 + kt), AS3(&As[c0 * 8]), 16, 0, 0);
    __builtin_amdgcn_global_load_lds(AS1(A + rA1 + kt), AS3(&As[c1 * 8]), 16, 0, 0);
    __builtin_amdgcn_global_load_lds(AS1(B + rB0 + kt), AS3(&Bs[c0 * 8]), 16, 0, 0);
    __builtin_amdgcn_global_load_lds(AS1(B + rB1 + kt), AS3(&Bs[c1 * 8]), 16, 0, 0);
    __syncthreads();
    bf16x8 af[4], bf[4];
#pragma unroll
    for (int i = 0; i < 4; ++i)
      af[i] = *reinterpret_cast<const bf16x8*>(&As[(wr * 64 + i * 16 + row16) * 32 + kg]);
#pragma unroll
    for (int j = 0; j < 4; ++j)
      bf[j] = *reinterpret_cast<const bf16x8*>(&Bs[(wc * 64 + j * 16 + row16) * 32 + kg]);
#pragma unroll
    for (int i = 0; i < 4; ++i)
#pragma unroll
      for (int j = 0; j < 4; ++j)
        acc[i][j] = __builtin_amdgcn_mfma_f32_16x16x32_bf16(af[i], bf[j], acc[i][j], 0, 0, 0);
    __syncthreads();
  }
  int rsub = (lane >> 4) << 2;
#pragma unroll
  for (int i = 0; i < 4; ++i)
#pragma unroll
    for (int j = 0; j < 4; ++j) {
      size_t base = (size_t)(m0 + wr * 64 + i * 16 + rsub) * N + (n0 + wc * 64 + j * 16 + row16);
#pragma unroll
      for (int reg = 0; reg < 4; ++reg) {
        if constexpr (BF16OUT) ((short*)Cv)[base + (size_t)reg * N] = f2b(acc[i][j][reg]);
        else                   ((float*)Cv)[base + (size_t)reg * N] = acc[i][j][reg];
      }
    }
}

// ---------------- flash attention (causal, GQA) ----------------
// grid (16 pairs, 32 heads); block p does qb=31-p then qb=p (33 units const).
// 4 waves x 16 q-rows; KV tile = 64; K/V double-buffered, prefetch-before-compute
// (T3-minimum). K/V staged via global_load_lds(16B) into LINEAR LDS with
// XOR-pre-swizzled SOURCE; reads XOR byte bits 4..6 with (row&7)<<4 ->
// conflict-free ds_read_b128. Q pre-scaled by 1/sqrt(D)*log2e -> exp2 softmax.
__global__ __launch_bounds__(256)
void attn_k(const short* __restrict__ Qr, const short* __restrict__ Kr,
            const short* __restrict__ Vt, short* __restrict__ Ob) {
  constexpr int PP = 72;              // P_lds row stride (shorts); 144B = 9*16 keeps b128 aligned
  __shared__ short Kl[2][64 * 128];   // 2 x 16 KB
  __shared__ short Vl[2][128 * 64];   // 2 x 16 KB
  __shared__ short Pl[4][16 * PP];    // 9 KB (per-wave slice)   -> 73 KB total, 2 blocks/CU
  int pr  = blockIdx.x;               // pair index 0..15
  int h   = blockIdx.y;
  int kvh = h >> 2;                   // G = H/KV = 4
  int tid = threadIdx.x, wave = tid >> 6, lane = tid & 63;
  int row16 = lane & 15, kg = (lane >> 4) << 3, rsub = (lane >> 4) << 2;
  int colb  = (lane >> 4) << 4;       // byte col offset of this lane's k-group
  int swz   = (row16 & 7) << 4;       // read-side XOR

  const short* Kb = Kr + (size_t)kvh * S_LEN * HD;
  const short* Vb = Vt + (size_t)kvh * HD * S_LEN;

  // tile-independent staging offsets (shorts)
  int kso[4], vso[4], llo[4];
#pragma unroll
  for (int r = 0; r < 4; ++r) {
    int c = tid + r * 256;
    llo[r] = c * 8;
    int krow = c >> 4, ch = c & 15;
    int sch = (ch & 8) | ((ch ^ krow) & 7);
    kso[r] = krow * HD + sch * 8;
    int dr = c >> 3, vch = c & 7;
    int vsch = (vch ^ dr) & 7;
    vso[r] = dr * S_LEN + vsch * 8;
  }

#define STAGE(BUF, KT) do {                                                      \
    const short* Kt_ = Kb + (size_t)(KT) * 64 * HD;                              \
    const short* Vt_ = Vb + (KT) * 64;                                           \
    _Pragma("unroll")                                                            \
    for (int r_ = 0; r_ < 4; ++r_)                                               \
      __builtin_amdgcn_global_load_lds(AS1(Kt_ + kso[r_]),                       \
                                       AS3(&Kl[BUF][llo[r_]]), 16, 0, 0);        \
    _Pragma("unroll")                                                            \
    for (int r_ = 0; r_ < 4; ++r_)                                               \
      __builtin_amdgcn_global_load_lds(AS1(Vt_ + vso[r_]),                       \
                                       AS3(&Vl[BUF][llo[r_]]), 16, 0, 0);        \
  } while (0)

  STAGE(0, 0);                        // prologue for first half

  for (int half = 0; half < 2; ++half) {
    int qb = half ? pr : (31 - pr);
    int qrow0 = qb * 64 + wave * 16;

    bf16x8 qf[4];
    {
      const short* qp = Qr + ((size_t)h * S_LEN + qrow0 + row16) * HD + kg;
#pragma unroll
      for (int ks = 0; ks < 4; ++ks)
        qf[ks] = *reinterpret_cast<const bf16x8*>(qp + ks * 32);
    }
    f32x4 o[8] = {};
    float mrow[4], lrow[4];
#pragma unroll
    for (int r = 0; r < 4; ++r) { mrow[r] = -3.0e38f; lrow[r] = 0.0f; }

    for (int kt = 0; kt <= qb; ++kt) {
      int cur = kt & 1;
      __syncthreads();                          // buf[cur] staged; buf[cur^1] free
      if (kt < qb) STAGE(cur ^ 1, kt + 1);      // prefetch overlaps compute below

      // S = Q K^T (16 rows x 64 keys per wave), log2-scaled domain
      f32x4 s4[4];
      __builtin_amdgcn_s_setprio(1);
#pragma unroll
      for (int nc = 0; nc < 4; ++nc) {
        const char* rowp = (const char*)&Kl[cur][0] + (nc * 16 + row16) * 256;
        f32x4 a = {};
#pragma unroll
        for (int ks = 0; ks < 4; ++ks) {
          bf16x8 kf = *reinterpret_cast<const bf16x8*>(rowp + ((ks * 64 + colb) ^ swz));
          a = __builtin_amdgcn_mfma_f32_16x16x32_bf16(qf[ks], kf, a, 0, 0, 0);
        }
        s4[nc] = a;
      }
      __builtin_amdgcn_s_setprio(0);

      // causal mask + tile row-max
      bool diag = (kt == qb);
      float mt[4] = {-3.0e38f, -3.0e38f, -3.0e38f, -3.0e38f};
#pragma unroll
      for (int nc = 0; nc < 4; ++nc)
#pragma unroll
        for (int reg = 0; reg < 4; ++reg) {
          float v = s4[nc][reg];
          if (diag && (kt * 64 + nc * 16 + row16) > (qrow0 + rsub + reg)) v = -3.0e38f;
          s4[nc][reg] = v;
          mt[reg] = fmaxf(mt[reg], v);
        }
#pragma unroll
      for (int reg = 0; reg < 4; ++reg)
#pragma unroll
        for (int off = 1; off < 16; off <<= 1)
          mt[reg] = fmaxf(mt[reg], __shfl_xor(mt[reg], off));

      // online softmax (base-2 domain)
      float sc[4], st[4];
#pragma unroll
      for (int reg = 0; reg < 4; ++reg) {
        float mnew = fmaxf(mrow[reg], mt[reg]);
        sc[reg] = exp2f(mrow[reg] - mnew);
        mrow[reg] = mnew;
        st[reg] = 0.0f;
      }
#pragma unroll
      for (int nc = 0; nc < 4; ++nc)
#pragma unroll
        for (int reg = 0; reg < 4; ++reg) {
          float p = exp2f(s4[nc][reg] - mrow[reg]);
          s4[nc][reg] = p;
          st[reg] += p;
        }
#pragma unroll
      for (int reg = 0; reg < 4; ++reg) {
#pragma unroll
        for (int off = 1; off < 16; off <<= 1)
          st[reg] += __shfl_xor(st[reg], off);
        lrow[reg] = lrow[reg] * sc[reg] + st[reg];
      }
#pragma unroll
      for (int i = 0; i < 8; ++i) {
        f32x4 t = o[i];
        t[0] *= sc[0]; t[1] *= sc[1]; t[2] *= sc[2]; t[3] *= sc[3];
        o[i] = t;
      }

      // P -> LDS (C layout -> [row][key]) then back as A-frag (same-wave RAW)
#pragma unroll
      for (int nc = 0; nc < 4; ++nc)
#pragma unroll
        for (int reg = 0; reg < 4; ++reg)
          Pl[wave][(rsub + reg) * PP + nc * 16 + row16] = f2b(s4[nc][reg]);

      // O += P V
      __builtin_amdgcn_s_setprio(1);
#pragma unroll
      for (int ks = 0; ks < 2; ++ks) {
        bf16x8 pf = *reinterpret_cast<const bf16x8*>(&Pl[wave][row16 * PP + ks * 32 + kg]);
#pragma unroll
        for (int nc = 0; nc < 8; ++nc) {
          const char* rowp = (const char*)&Vl[cur][0] + (nc * 16 + row16) * 128;
          bf16x8 vf = *reinterpret_cast<const bf16x8*>(rowp + ((ks * 64 + colb) ^ swz));
          o[nc] = __builtin_amdgcn_mfma_f32_16x16x32_bf16(pf, vf, o[nc], 0, 0, 0);
        }
      }
      __builtin_amdgcn_s_setprio(0);
    }

    __syncthreads();                  // all waves done with both buffers
    if (half == 0) STAGE(0, 0);       // prefetch next half's first tile (overlaps epilogue)

    // epilogue: O /= l, write [S][H*D] bf16
#pragma unroll
    for (int nc = 0; nc < 8; ++nc)
#pragma unroll
      for (int reg = 0; reg < 4; ++reg) {
        float val = o[nc][reg] * (1.0f / lrow[reg]);
        int srow = qrow0 + rsub + reg;
        Ob[(size_t)srow * HID_SZ + h * HD + nc * 16 + row16] = f2b(val);
      }
  }
#undef STAGE
}

// ---------------- launch ----------------
extern "C" void kernel_launch(void* const* d_in, const int* in_sizes, int n_in,
                              void* d_out, int out_size, void* d_ws, size_t ws_size,
                              hipStream_t stream) {
  const float* x   = (const float*)d_in[0];
  const float* wq  = (const float*)d_in[1];
  const float* wk  = (const float*)d_in[2];
  const float* wv  = (const float*)d_in[3];
  const float* wo  = (const float*)d_in[4];
  const float* qnw = (const float*)d_in[5];
  const float* knw = (const float*)d_in[6];
  float* out = (float*)d_out;

  // workspace (aliased; 113 MB):
  //   [0,16M)     xb bf16 [2048][4096]  -> later attnb bf16
  //   [16M,64M)   wqkvb bf16 [6144][4096] -> later wob bf16 [4096][4096] (32M)
  //   [64M,88M)   qkvb bf16 [2048][6144]
  //   [88M,104M)  qr bf16 [32][2048][128]
  //   [104M,108M) kr bf16 [8][2048][128]
  //   [108M,112M) vt bf16 [8][128][2048]
  //   [112M,113M) cosT/sinT fp32 [2048][64]
  char* ws = (char*)d_ws;
  short* xb    = (short*)(ws);
  short* attnb = (short*)(ws);
  short* wqkvb = (short*)(ws + (16ull  << 20));
  short* wob   = (short*)(ws + (16ull  << 20));
  short* qkvb  = (short*)(ws + (64ull  << 20));
  short* qr    = (short*)(ws + (88ull  << 20));
  short* kr    = (short*)(ws + (104ull << 20));
  short* vt    = (short*)(ws + (108ull << 20));
  float* cosT  = (float*)(ws + (112ull << 20));
  float* sinT  = (float*)(ws + (112ull << 20) + (512ull << 10));

  // 1) convert x + packed [wq;wk;wv] to bf16
  cvt_f32_bf16<<<8192,  256, 0, stream>>>(x,  xb,    2097152);
  cvt_f32_bf16<<<16384, 256, 0, stream>>>(wq, wqkvb,                       4194304);
  cvt_f32_bf16<<<4096,  256, 0, stream>>>(wk, wqkvb + (size_t)4096 * 4096, 1048576);
  cvt_f32_bf16<<<4096,  256, 0, stream>>>(wv, wqkvb + (size_t)5120 * 4096, 1048576);

  // 2) RoPE tables
  rope_tables_k<<<2048, 64, 0, stream>>>(cosT, sinT);

  // 3) fused QKV projection -> bf16 [2048][6144]
  gemm_bt_k<true><<<dim3(48, 16), 256, 0, stream>>>(xb, wqkvb, qkvb, 2048, 6144, 4096);

  // 4) wo -> bf16 (after QKV GEMM; overwrites wqkvb region)
  cvt_f32_bf16<<<16384, 256, 0, stream>>>(wo, wob, 4194304);

  // 5) RMSNorm + RoPE (Q pre-scaled by 1/sqrt(D)*log2e); V -> [KV][D][S]
  rmsrope_k<<<16384, 256, 0, stream>>>(qkvb, 0,    qnw, cosT, sinT, qr, NH,  QSCALE);
  rmsrope_k<<<4096,  256, 0, stream>>>(qkvb, 4096, knw, cosT, sinT, kr, NKV, 1.0f);
  vtrans_k<<<dim3(32, 2, 8), 256, 0, stream>>>(qkvb, vt);

  // 6) causal GQA flash attention -> attnb [S][H*D] bf16 (overwrites xb region)
  attn_k<<<dim3(16, 32), 256, 0, stream>>>(qr, kr, vt, attnb);

  // 7) output projection -> d_out fp32
  gemm_bt_k<false><<<dim3(32, 16), 256, 0, stream>>>(attnb, wob, out, 2048, 4096, 4096);

  (void)in_sizes; (void)n_in; (void)out_size; (void)ws_size;
}